// Round 7
// baseline (368.667 us; speedup 1.0000x reference)
//
#include <hip/hip_runtime.h>

#define NPAD 256
#define LDSX 1536

typedef float v2f __attribute__((ext_vector_type(2)));

// Forced VOP3P packed f32 ops (compiler refuses to form these itself - round 6
// came back scalarized with VGPR=64 and zero delta).
__device__ __forceinline__ v2f pk_mul(v2f a, v2f b) {
  v2f d;
  asm("v_pk_mul_f32 %0, %1, %2" : "=v"(d) : "v"(a), "v"(b));
  return d;
}
__device__ __forceinline__ v2f pk_fma(v2f a, v2f b, v2f c) {
  v2f d;
  asm("v_pk_fma_f32 %0, %1, %2, %3" : "=v"(d) : "v"(a), "v"(b), "v"(c));
  return d;
}
// c += (z == m) ? 1 : 0 in 2 VALU ops via carry-add. Clobbers vcc.
__device__ __forceinline__ void cnt_eq(int& c, float z, float m) {
  asm("v_cmp_eq_f32 vcc, %1, %2\n\t"
      "v_addc_co_u32 %0, vcc, 0, %0, vcc"
      : "+v"(c) : "v"(z), "v"(m) : "vcc");
}

// Sum across 64 lanes via DPP; valid result lands in lane 63. Pure VALU.
__device__ __forceinline__ float wredf(float x) {
  x += __int_as_float(__builtin_amdgcn_update_dpp(0, __float_as_int(x), 0x111, 0xf, 0xf, true)); // row_shr:1
  x += __int_as_float(__builtin_amdgcn_update_dpp(0, __float_as_int(x), 0x112, 0xf, 0xf, true)); // row_shr:2
  x += __int_as_float(__builtin_amdgcn_update_dpp(0, __float_as_int(x), 0x114, 0xf, 0xf, true)); // row_shr:4
  x += __int_as_float(__builtin_amdgcn_update_dpp(0, __float_as_int(x), 0x118, 0xf, 0xf, true)); // row_shr:8
  x += __int_as_float(__builtin_amdgcn_update_dpp(0, __float_as_int(x), 0x142, 0xa, 0xf, true)); // bcast15 rows 1,3
  x += __int_as_float(__builtin_amdgcn_update_dpp(0, __float_as_int(x), 0x143, 0xc, 0xf, true)); // bcast31 rows 2,3
  return x;
}
__device__ __forceinline__ int wredi(int x) {
  x += __builtin_amdgcn_update_dpp(0, x, 0x111, 0xf, 0xf, true);
  x += __builtin_amdgcn_update_dpp(0, x, 0x112, 0xf, 0xf, true);
  x += __builtin_amdgcn_update_dpp(0, x, 0x114, 0xf, 0xf, true);
  x += __builtin_amdgcn_update_dpp(0, x, 0x118, 0xf, 0xf, true);
  x += __builtin_amdgcn_update_dpp(0, x, 0x142, 0xa, 0xf, true);
  x += __builtin_amdgcn_update_dpp(0, x, 0x143, 0xc, 0xf, true);
  return x;
}

// Block = one (n, di, diff). 4 waves; each wave handles 8 groups; 64 lanes
// cover 64 consecutive t per iteration. Kernels paired (2p,2p+1) against a
// broadcast tap value -> 36 v_pk_fma_f32 per position instead of 72 v_fmac.
__global__ void __launch_bounds__(256, 3) hydra_kernel(
    const float* __restrict__ X, const float* __restrict__ W,
    float* __restrict__ out) {
  __shared__ float xs[LDSX];

  const int b = blockIdx.x;
  const int n = b / 14;
  const int r = b - n * 14;          // di*2 + diff
  const int diff = r & 1;
  const int d = 1 << (r >> 1);       // dilation
  const int Lz = 1024 - diff;        // output length (1023 for diff branch)
  const float* xrow = X + n * 1024;
  const int tid = threadIdx.x;
  const float qnan = __int_as_float(0x7fc00000);

  // Stage padded input row (zeros in [0,256) and [256+Lz,1536))
  for (int i = tid; i < LDSX; i += 256) {
    int t = i - NPAD;
    float v = 0.0f;
    if (t >= 0 && t < Lz) v = diff ? (xrow[t + 1] - xrow[t]) : xrow[t];
    xs[i] = v;
  }
  __syncthreads();

  const int lane = tid & 63;
  const int wv = tid >> 6;
  const float* wb = W + r * 2304;                    // (di,diff) filter bank: 256*9
  float* outb = out + (size_t)n * 7168 + r * 512;    // [cmax(256) | cmin(256)]

  for (int gp = 0; gp < 8; ++gp) {
    const int g = wv * 8 + gp;

    // 72 wave-uniform weights -> 36 kernel-pair registers:
    // w2[p*9+j] = { w[2p][j], w[2p+1][j] }
    float w[72];
    {
      const float4* w4 = (const float4*)(wb + g * 72);
      #pragma unroll
      for (int q = 0; q < 18; ++q) {
        float4 v = w4[q];
        w[q * 4 + 0] = v.x; w[q * 4 + 1] = v.y;
        w[q * 4 + 2] = v.z; w[q * 4 + 3] = v.w;
      }
    }
    v2f w2[36];
    #pragma unroll
    for (int p = 0; p < 4; ++p)
      #pragma unroll
      for (int j = 0; j < 9; ++j)
        w2[p * 9 + j] = (v2f){w[(2 * p) * 9 + j], w[(2 * p + 1) * 9 + j]};

    v2f cmax2[4];
    int cmin[8];
    #pragma unroll
    for (int p = 0; p < 4; ++p) cmax2[p] = (v2f){0.0f, 0.0f};
    #pragma unroll
    for (int k = 0; k < 8; ++k) cmin[k] = 0;

    const int base0 = NPAD - 4 * d + lane;           // index of tap 0 at t=lane

    #pragma unroll 2
    for (int it = 0; it < 16; ++it) {
      const int t = it * 64 + lane;

      // conv of 4 kernel pairs; per-kernel tap order identical to the scalar
      // version -> bitwise-same z values (absmax must stay 3.0).
      v2f z2[4];
      {
        float x0 = xs[base0 + it * 64];
        v2f xx0 = (v2f){x0, x0};
        #pragma unroll
        for (int p = 0; p < 4; ++p) z2[p] = pk_mul(w2[p * 9], xx0);
      }
      #pragma unroll
      for (int j = 1; j < 9; ++j) {
        float xj = xs[base0 + it * 64 + j * d];
        v2f xx = (v2f){xj, xj};
        #pragma unroll
        for (int p = 0; p < 4; ++p)
          z2[p] = pk_fma(w2[p * 9 + j], xx, z2[p]);
      }

      const float mx = fmaxf(
          fmaxf(fmaxf(z2[0].x, z2[0].y), fmaxf(z2[1].x, z2[1].y)),
          fmaxf(fmaxf(z2[2].x, z2[2].y), fmaxf(z2[3].x, z2[3].y)));
      const float mn = fminf(
          fminf(fminf(z2[0].x, z2[0].y), fminf(z2[1].x, z2[1].y)),
          fminf(fminf(z2[2].x, z2[2].y), fminf(z2[3].x, z2[3].y)));
      // Fold the tail-validity guard into the min target: z == NaN is never
      // true, so invalid lanes count nothing. (cmax needs no guard: padded
      // z==0 adds 0.)
      const float mn_eff = (t < Lz) ? mn : qnan;

      #pragma unroll
      for (int p = 0; p < 4; ++p) {
        cmax2[p].x += (z2[p].x == mx) ? z2[p].x : 0.0f;
        cmax2[p].y += (z2[p].y == mx) ? z2[p].y : 0.0f;
        cnt_eq(cmin[2 * p],     z2[p].x, mn_eff);
        cnt_eq(cmin[2 * p + 1], z2[p].y, mn_eff);
      }
    }

    float cmax[8];
    #pragma unroll
    for (int p = 0; p < 4; ++p) { cmax[2 * p] = cmax2[p].x; cmax[2 * p + 1] = cmax2[p].y; }
    #pragma unroll
    for (int k = 0; k < 8; ++k) cmax[k] = wredf(cmax[k]);
    int cminr[8];
    #pragma unroll
    for (int k = 0; k < 8; ++k) cminr[k] = wredi(cmin[k]);

    if (lane == 63) {
      float4 a0 = make_float4(cmax[0], cmax[1], cmax[2], cmax[3]);
      float4 a1 = make_float4(cmax[4], cmax[5], cmax[6], cmax[7]);
      float4 b0 = make_float4((float)cminr[0], (float)cminr[1],
                              (float)cminr[2], (float)cminr[3]);
      float4 b1 = make_float4((float)cminr[4], (float)cminr[5],
                              (float)cminr[6], (float)cminr[7]);
      float4* pm = (float4*)(outb + g * 8);
      pm[0] = a0; pm[1] = a1;
      float4* pn = (float4*)(outb + 256 + g * 8);
      pn[0] = b0; pn[1] = b1;
    }
  }
}

extern "C" void kernel_launch(void* const* d_in, const int* in_sizes, int n_in,
                              void* d_out, int out_size, void* d_ws, size_t ws_size,
                              hipStream_t stream) {
  const float* X = (const float*)d_in[0];   // (256,1,1024) f32
  const float* W = (const float*)d_in[1];   // (7,2,256,1,9) f32, normalized
  float* out = (float*)d_out;               // (256,7168) f32
  hydra_kernel<<<dim3(256 * 14), dim3(256), 0, stream>>>(X, W, out);
}

// Round 8
// 318.886 us; speedup vs baseline: 1.1561x; 1.1561x over previous
//
#include <hip/hip_runtime.h>

#define NPAD 256
#define LDSX 1536

// Force a wave-uniform float into an SGPR (weights are wave-uniform; holding
// all 72 in SGPRs kills the in-loop s_load chunk reloads seen as VGPR=64/SGPR=48).
__device__ __forceinline__ float to_sgpr(float v) {
  return __int_as_float(__builtin_amdgcn_readfirstlane(__float_as_int(v)));
}

// Sum across 64 lanes via DPP; valid result lands in lane 63. Pure VALU.
__device__ __forceinline__ float wredf(float x) {
  x += __int_as_float(__builtin_amdgcn_update_dpp(0, __float_as_int(x), 0x111, 0xf, 0xf, true)); // row_shr:1
  x += __int_as_float(__builtin_amdgcn_update_dpp(0, __float_as_int(x), 0x112, 0xf, 0xf, true)); // row_shr:2
  x += __int_as_float(__builtin_amdgcn_update_dpp(0, __float_as_int(x), 0x114, 0xf, 0xf, true)); // row_shr:4
  x += __int_as_float(__builtin_amdgcn_update_dpp(0, __float_as_int(x), 0x118, 0xf, 0xf, true)); // row_shr:8
  x += __int_as_float(__builtin_amdgcn_update_dpp(0, __float_as_int(x), 0x142, 0xa, 0xf, true)); // bcast15 rows 1,3
  x += __int_as_float(__builtin_amdgcn_update_dpp(0, __float_as_int(x), 0x143, 0xc, 0xf, true)); // bcast31 rows 2,3
  return x;
}
__device__ __forceinline__ int wredi(int x) {
  x += __builtin_amdgcn_update_dpp(0, x, 0x111, 0xf, 0xf, true);
  x += __builtin_amdgcn_update_dpp(0, x, 0x112, 0xf, 0xf, true);
  x += __builtin_amdgcn_update_dpp(0, x, 0x114, 0xf, 0xf, true);
  x += __builtin_amdgcn_update_dpp(0, x, 0x118, 0xf, 0xf, true);
  x += __builtin_amdgcn_update_dpp(0, x, 0x142, 0xa, 0xf, true);
  x += __builtin_amdgcn_update_dpp(0, x, 0x143, 0xc, 0xf, true);
  return x;
}

// Block = one (n, di, diff). 4 waves; each wave handles 8 groups; 64 lanes
// cover 64 consecutive t positions per iteration (16 iters over 1024).
// Weights live in SGPRs (v_fmac_f32 v,s,v); per-lane VGPR set stays ~50.
__global__ void __launch_bounds__(256, 3) hydra_kernel(
    const float* __restrict__ X, const float* __restrict__ W,
    float* __restrict__ out) {
  __shared__ float xs[LDSX];

  const int b = blockIdx.x;
  const int n = b / 14;
  const int r = b - n * 14;          // di*2 + diff
  const int diff = r & 1;
  const int d = 1 << (r >> 1);       // dilation
  const int Lz = 1024 - diff;        // output length (1023 for diff branch)
  const float* xrow = X + n * 1024;
  const int tid = threadIdx.x;
  const float qnan = __int_as_float(0x7fc00000);

  // Stage padded input row (zeros in [0,256) and [256+Lz,1536))
  for (int i = tid; i < LDSX; i += 256) {
    int t = i - NPAD;
    float v = 0.0f;
    if (t >= 0 && t < Lz) v = diff ? (xrow[t + 1] - xrow[t]) : xrow[t];
    xs[i] = v;
  }
  __syncthreads();

  const int lane = tid & 63;
  const int wv = tid >> 6;
  const float* wb = W + r * 2304;                    // (di,diff) filter bank: 256*9
  float* outb = out + (size_t)n * 7168 + r * 512;    // [cmax(256) | cmin(256)]

  for (int gp = 0; gp < 8; ++gp) {
    const int g = wv * 8 + gp;

    // 72 wave-uniform weights: vector-load then pin into SGPRs (one-time cost
    // of 72 readfirstlane per group, amortized over 16 iterations).
    float w[72];
    {
      const float4* w4 = (const float4*)(wb + g * 72);
      #pragma unroll
      for (int q = 0; q < 18; ++q) {
        float4 v = w4[q];
        w[q * 4 + 0] = to_sgpr(v.x); w[q * 4 + 1] = to_sgpr(v.y);
        w[q * 4 + 2] = to_sgpr(v.z); w[q * 4 + 3] = to_sgpr(v.w);
      }
    }

    float cmax[8];
    int cmin[8];
    #pragma unroll
    for (int k = 0; k < 8; ++k) { cmax[k] = 0.0f; cmin[k] = 0; }

    const int base0 = NPAD - 4 * d + lane;           // index of tap 0 at t=lane

    #pragma unroll 4
    for (int it = 0; it < 16; ++it) {
      const int t = it * 64 + lane;

      float xv[9];
      #pragma unroll
      for (int j = 0; j < 9; ++j) xv[j] = xs[base0 + it * 64 + j * d];

      float z[8];
      #pragma unroll
      for (int k = 0; k < 8; ++k) {
        float a = w[k * 9] * xv[0];
        #pragma unroll
        for (int j = 1; j < 9; ++j) a = fmaf(w[k * 9 + j], xv[j], a);
        z[k] = a;
      }

      // max/min trees shaped for v_max3/v_min3 fusion (fmax/fmin are exactly
      // associative on NaN-free data -> bitwise-identical mx/mn).
      const float mA = fmaxf(fmaxf(z[0], z[1]), z[2]);
      const float mB = fmaxf(fmaxf(z[3], z[4]), z[5]);
      const float mC = fmaxf(z[6], z[7]);
      const float mx = fmaxf(fmaxf(mA, mB), mC);
      const float iA = fminf(fminf(z[0], z[1]), z[2]);
      const float iB = fminf(fminf(z[3], z[4]), z[5]);
      const float iC = fminf(z[6], z[7]);
      const float mn = fminf(fminf(iA, iB), iC);
      // Tail guard folded into the min target: z==NaN is never true.
      // (cmax needs no guard: padded z==0 adds 0.)
      const float mn_eff = (t < Lz) ? mn : qnan;

      #pragma unroll
      for (int k = 0; k < 8; ++k) {
        cmax[k] += (z[k] == mx) ? z[k] : 0.0f;
        cmin[k] += (z[k] == mn_eff) ? 1 : 0;
      }
    }

    #pragma unroll
    for (int k = 0; k < 8; ++k) cmax[k] = wredf(cmax[k]);
    int cminr[8];
    #pragma unroll
    for (int k = 0; k < 8; ++k) cminr[k] = wredi(cmin[k]);

    if (lane == 63) {
      float4 a0 = make_float4(cmax[0], cmax[1], cmax[2], cmax[3]);
      float4 a1 = make_float4(cmax[4], cmax[5], cmax[6], cmax[7]);
      float4 b0 = make_float4((float)cminr[0], (float)cminr[1],
                              (float)cminr[2], (float)cminr[3]);
      float4 b1 = make_float4((float)cminr[4], (float)cminr[5],
                              (float)cminr[6], (float)cminr[7]);
      float4* pm = (float4*)(outb + g * 8);
      pm[0] = a0; pm[1] = a1;
      float4* pn = (float4*)(outb + 256 + g * 8);
      pn[0] = b0; pn[1] = b1;
    }
  }
}

extern "C" void kernel_launch(void* const* d_in, const int* in_sizes, int n_in,
                              void* d_out, int out_size, void* d_ws, size_t ws_size,
                              hipStream_t stream) {
  const float* X = (const float*)d_in[0];   // (256,1,1024) f32
  const float* W = (const float*)d_in[1];   // (7,2,256,1,9) f32, normalized
  float* out = (float*)d_out;               // (256,7168) f32
  hydra_kernel<<<dim3(256 * 14), dim3(256), 0, stream>>>(X, W, out);
}

// Round 9
// 307.019 us; speedup vs baseline: 1.2008x; 1.0386x over previous
//
#include <hip/hip_runtime.h>

#define NPAD 256
#define LDSX 1536

// Pin a wave-uniform float into an SGPR (weights); folds away if the compiler
// already used s_load for the uniform address.
__device__ __forceinline__ float to_sgpr(float v) {
  return __int_as_float(__builtin_amdgcn_readfirstlane(__float_as_int(v)));
}

// c += (z == m) ? 1 : 0 in 2 VALU ops (cmp + carry-add). Clobbers vcc; fine:
// kernel is issue-bound, not latency-bound. z==NaN never true -> m=NaN guards.
__device__ __forceinline__ void cnt_eq(int& c, float z, float m) {
  asm("v_cmp_eq_f32 vcc, %1, %2\n\t"
      "v_addc_co_u32 %0, vcc, 0, %0, vcc"
      : "+v"(c) : "v"(z), "v"(m) : "vcc");
}

// Sum across 64 lanes via DPP; valid result lands in lane 63. Pure VALU.
__device__ __forceinline__ float wredf(float x) {
  x += __int_as_float(__builtin_amdgcn_update_dpp(0, __float_as_int(x), 0x111, 0xf, 0xf, true)); // row_shr:1
  x += __int_as_float(__builtin_amdgcn_update_dpp(0, __float_as_int(x), 0x112, 0xf, 0xf, true)); // row_shr:2
  x += __int_as_float(__builtin_amdgcn_update_dpp(0, __float_as_int(x), 0x114, 0xf, 0xf, true)); // row_shr:4
  x += __int_as_float(__builtin_amdgcn_update_dpp(0, __float_as_int(x), 0x118, 0xf, 0xf, true)); // row_shr:8
  x += __int_as_float(__builtin_amdgcn_update_dpp(0, __float_as_int(x), 0x142, 0xa, 0xf, true)); // bcast15 rows 1,3
  x += __int_as_float(__builtin_amdgcn_update_dpp(0, __float_as_int(x), 0x143, 0xc, 0xf, true)); // bcast31 rows 2,3
  return x;
}
__device__ __forceinline__ int wredi(int x) {
  x += __builtin_amdgcn_update_dpp(0, x, 0x111, 0xf, 0xf, true);
  x += __builtin_amdgcn_update_dpp(0, x, 0x112, 0xf, 0xf, true);
  x += __builtin_amdgcn_update_dpp(0, x, 0x114, 0xf, 0xf, true);
  x += __builtin_amdgcn_update_dpp(0, x, 0x118, 0xf, 0xf, true);
  x += __builtin_amdgcn_update_dpp(0, x, 0x142, 0xa, 0xf, true);
  x += __builtin_amdgcn_update_dpp(0, x, 0x143, 0xc, 0xf, true);
  return x;
}

// One wave processes 2 groups for all 1024 positions of one (n, di, diff) row.
// D is compile-time: all 9 tap reads (and the 15 unrolled-its' bases) become
// ds_read with immediate offsets -> near-zero address VALU in the hot loop.
template <int D>
__device__ __forceinline__ void conv_body(
    const float* __restrict__ xs, int diff, int lane, int wv, int gh,
    const float* __restrict__ wb, float* __restrict__ outb) {
  const int Lz = 1024 - diff;
  const float qnan = __int_as_float(0x7fc00000);

  for (int gp = 0; gp < 2; ++gp) {
    const int g = gh * 8 + wv * 2 + gp;

    // 72 wave-uniform weights pinned in SGPRs.
    float w[72];
    {
      const float4* w4 = (const float4*)(wb + g * 72);
      #pragma unroll
      for (int q = 0; q < 18; ++q) {
        float4 v = w4[q];
        w[q * 4 + 0] = to_sgpr(v.x); w[q * 4 + 1] = to_sgpr(v.y);
        w[q * 4 + 2] = to_sgpr(v.z); w[q * 4 + 3] = to_sgpr(v.w);
      }
    }

    float cmax[8];
    int cmin[8];
    #pragma unroll
    for (int k = 0; k < 8; ++k) { cmax[k] = 0.0f; cmin[k] = 0; }

    const float* xp = xs + (NPAD - 4 * D) + lane;   // tap-0 addr at t=lane

    // it = 0..14: every lane's position t = it*64+lane <= 959 < 1023 -> no guard.
    #pragma unroll 3
    for (int it = 0; it < 15; ++it) {
      float xv[9];
      #pragma unroll
      for (int j = 0; j < 9; ++j) xv[j] = xp[it * 64 + j * D];  // imm offsets

      float z[8];
      #pragma unroll
      for (int k = 0; k < 8; ++k) {
        float a = w[k * 9] * xv[0];
        #pragma unroll
        for (int j = 1; j < 9; ++j) a = fmaf(w[k * 9 + j], xv[j], a);
        z[k] = a;
      }

      // shaped for v_max3/v_min3 fusion (exact associativity, NaN-free data)
      const float mx = fmaxf(fmaxf(fmaxf(fmaxf(z[0], z[1]), z[2]),
                                   fmaxf(fmaxf(z[3], z[4]), z[5])),
                             fmaxf(z[6], z[7]));
      const float mn = fminf(fminf(fminf(fminf(z[0], z[1]), z[2]),
                                   fminf(fminf(z[3], z[4]), z[5])),
                             fminf(z[6], z[7]));
      #pragma unroll
      for (int k = 0; k < 8; ++k) {
        cmax[k] += (z[k] == mx) ? z[k] : 0.0f;
        cnt_eq(cmin[k], z[k], mn);
      }
    }

    // it = 15 peeled: t = 960+lane; lane 63 invalid when diff=1 (Lz=1023).
    // Guard BOTH counts via NaN-ed comparand (z==NaN never true). This also
    // fixes the r5-r8 latent hazard of adding the t=1023 partial-conv z.
    {
      float xv[9];
      #pragma unroll
      for (int j = 0; j < 9; ++j) xv[j] = xp[15 * 64 + j * D];

      float z[8];
      #pragma unroll
      for (int k = 0; k < 8; ++k) {
        float a = w[k * 9] * xv[0];
        #pragma unroll
        for (int j = 1; j < 9; ++j) a = fmaf(w[k * 9 + j], xv[j], a);
        z[k] = a;
      }
      const float mx = fmaxf(fmaxf(fmaxf(fmaxf(z[0], z[1]), z[2]),
                                   fmaxf(fmaxf(z[3], z[4]), z[5])),
                             fmaxf(z[6], z[7]));
      const float mn = fminf(fminf(fminf(fminf(z[0], z[1]), z[2]),
                                   fminf(fminf(z[3], z[4]), z[5])),
                             fminf(z[6], z[7]));
      const bool valid = (960 + lane) < Lz;
      const float mx_eff = valid ? mx : qnan;
      const float mn_eff = valid ? mn : qnan;
      #pragma unroll
      for (int k = 0; k < 8; ++k) {
        cmax[k] += (z[k] == mx_eff) ? z[k] : 0.0f;
        cnt_eq(cmin[k], z[k], mn_eff);
      }
    }

    #pragma unroll
    for (int k = 0; k < 8; ++k) cmax[k] = wredf(cmax[k]);
    int cminr[8];
    #pragma unroll
    for (int k = 0; k < 8; ++k) cminr[k] = wredi(cmin[k]);

    if (lane == 63) {
      float4 a0 = make_float4(cmax[0], cmax[1], cmax[2], cmax[3]);
      float4 a1 = make_float4(cmax[4], cmax[5], cmax[6], cmax[7]);
      float4 b0 = make_float4((float)cminr[0], (float)cminr[1],
                              (float)cminr[2], (float)cminr[3]);
      float4 b1 = make_float4((float)cminr[4], (float)cminr[5],
                              (float)cminr[6], (float)cminr[7]);
      float4* pm = (float4*)(outb + g * 8);
      pm[0] = a0; pm[1] = a1;
      float4* pn = (float4*)(outb + 256 + g * 8);
      pn[0] = b0; pn[1] = b1;
    }
  }
}

// Block = (n, r, gh): 4 waves x 2 groups = 8 of the 32 groups of one row.
// 14336 blocks -> fine scheduling quantum (no 3.5-round tail), and low VGPR
// lets up to 8 blocks/CU be resident.
__global__ void __launch_bounds__(256, 3) hydra_kernel(
    const float* __restrict__ X, const float* __restrict__ W,
    float* __restrict__ out) {
  __shared__ float xs[LDSX];

  const int b = blockIdx.x;
  const int gh = b & 3;
  const int t1 = b >> 2;
  const int r = t1 % 14;             // di*2 + diff
  const int n = t1 / 14;
  const int diff = r & 1;
  const int di = r >> 1;
  const int Lz = 1024 - diff;
  const float* xrow = X + n * 1024;
  const int tid = threadIdx.x;

  // Stage padded input row (zeros in [0,256) and [256+Lz,1536))
  for (int i = tid; i < LDSX; i += 256) {
    int t = i - NPAD;
    float v = 0.0f;
    if (t >= 0 && t < Lz) v = diff ? (xrow[t + 1] - xrow[t]) : xrow[t];
    xs[i] = v;
  }
  __syncthreads();

  const int lane = tid & 63;
  const int wv = tid >> 6;
  const float* wb = W + r * 2304;                    // (di,diff) bank: 256*9
  float* outb = out + (size_t)n * 7168 + r * 512;    // [cmax(256) | cmin(256)]

  switch (di) {
    case 0: conv_body<1 >(xs, diff, lane, wv, gh, wb, outb); break;
    case 1: conv_body<2 >(xs, diff, lane, wv, gh, wb, outb); break;
    case 2: conv_body<4 >(xs, diff, lane, wv, gh, wb, outb); break;
    case 3: conv_body<8 >(xs, diff, lane, wv, gh, wb, outb); break;
    case 4: conv_body<16>(xs, diff, lane, wv, gh, wb, outb); break;
    case 5: conv_body<32>(xs, diff, lane, wv, gh, wb, outb); break;
    default: conv_body<64>(xs, diff, lane, wv, gh, wb, outb); break;
  }
}

extern "C" void kernel_launch(void* const* d_in, const int* in_sizes, int n_in,
                              void* d_out, int out_size, void* d_ws, size_t ws_size,
                              hipStream_t stream) {
  const float* X = (const float*)d_in[0];   // (256,1,1024) f32
  const float* W = (const float*)d_in[1];   // (7,2,256,1,9) f32, normalized
  float* out = (float*)d_out;               // (256,7168) f32
  hydra_kernel<<<dim3(256 * 14 * 4), dim3(256), 0, stream>>>(X, W, out);
}

// Round 10
// 292.986 us; speedup vs baseline: 1.2583x; 1.0479x over previous
//
#include <hip/hip_runtime.h>

#define NPAD 256
#define LDSX 1536

// Pin a wave-uniform value into scalar registers.
__device__ __forceinline__ float to_sgpr(float v) {
  return __int_as_float(__builtin_amdgcn_readfirstlane(__float_as_int(v)));
}

// c += (z == m) ? 1 : 0 in 2 VALU ops (cmp + carry-add). Clobbers vcc.
// m = NaN guards (z==NaN never true).
__device__ __forceinline__ void cnt_eq(int& c, float z, float m) {
  asm("v_cmp_eq_f32 vcc, %1, %2\n\t"
      "v_addc_co_u32 %0, vcc, 0, %0, vcc"
      : "+v"(c) : "v"(z), "v"(m) : "vcc");
}

// Sum across 64 lanes via DPP; valid result lands in lane 63. Pure VALU.
__device__ __forceinline__ float wredf(float x) {
  x += __int_as_float(__builtin_amdgcn_update_dpp(0, __float_as_int(x), 0x111, 0xf, 0xf, true)); // row_shr:1
  x += __int_as_float(__builtin_amdgcn_update_dpp(0, __float_as_int(x), 0x112, 0xf, 0xf, true)); // row_shr:2
  x += __int_as_float(__builtin_amdgcn_update_dpp(0, __float_as_int(x), 0x114, 0xf, 0xf, true)); // row_shr:4
  x += __int_as_float(__builtin_amdgcn_update_dpp(0, __float_as_int(x), 0x118, 0xf, 0xf, true)); // row_shr:8
  x += __int_as_float(__builtin_amdgcn_update_dpp(0, __float_as_int(x), 0x142, 0xa, 0xf, true)); // bcast15 rows 1,3
  x += __int_as_float(__builtin_amdgcn_update_dpp(0, __float_as_int(x), 0x143, 0xc, 0xf, true)); // bcast31 rows 2,3
  return x;
}
__device__ __forceinline__ int wredi(int x) {
  x += __builtin_amdgcn_update_dpp(0, x, 0x111, 0xf, 0xf, true);
  x += __builtin_amdgcn_update_dpp(0, x, 0x112, 0xf, 0xf, true);
  x += __builtin_amdgcn_update_dpp(0, x, 0x114, 0xf, 0xf, true);
  x += __builtin_amdgcn_update_dpp(0, x, 0x118, 0xf, 0xf, true);
  x += __builtin_amdgcn_update_dpp(0, x, 0x142, 0xa, 0xf, true);
  x += __builtin_amdgcn_update_dpp(0, x, 0x143, 0xc, 0xf, true);
  return x;
}

template <int D>
struct ConvCfg {
  static constexpr int S = (D >= 8) ? (64 / D) : 9;  // new taps per t+=64 step
  static constexpr int R = 9 - S;                    // taps reused from prev iter
};

// One wave processes 2 groups over all 1024 positions of one (n, di, diff) row.
// Software-pipelined: iteration it issues loads for it+1 (ds_read2-mergeable,
// cross-iter tap reuse for D>=8), then computes it from registers.
template <int D>
__device__ __forceinline__ void conv_body(
    const float* __restrict__ xs, int diff, int lane, int wv, int gh,
    const float* __restrict__ wb, float* __restrict__ outb) {
  constexpr int S = ConvCfg<D>::S;
  constexpr int R = ConvCfg<D>::R;
  const int Lz = 1024 - diff;
  const float qnan = __int_as_float(0x7fc00000);

  for (int gp = 0; gp < 2; ++gp) {
    const int g = gh * 8 + wv * 2 + gp;

    // Wave-uniform weight pointer (rfl'd offset -> provably uniform -> s_load);
    // value-rfl keeps them in SGPRs even if the s_load conversion fails.
    const float* wg = wb + __builtin_amdgcn_readfirstlane(g * 72);
    float w[72];
    #pragma unroll
    for (int i = 0; i < 72; ++i) w[i] = to_sgpr(wg[i]);

    float cmax[8];
    int cmin[8];
    #pragma unroll
    for (int k = 0; k < 8; ++k) { cmax[k] = 0.0f; cmin[k] = 0; }

    const float* xq = xs + (NPAD - 4 * D) + lane;   // tap-0 address at t=lane

    // Prologue: all 9 taps of it=0.
    float xv[9];
    #pragma unroll
    for (int j = 0; j < 9; ++j) xv[j] = xq[j * D];

    // it = 0..14 (positions <= 959 < 1023: no tail guard needed).
    #pragma unroll 5
    for (int it = 0; it < 15; ++it) {
      // Issue next iteration's new-tap loads FIRST (pipelining: their waitcnt
      // lands after this iteration's 72 FMAs). Rebased pointer keeps dword
      // offsets i*D <= 255 so pairs merge into ds_read2_b32.
      float xn[9];
      {
        const float* xb = xq + (it + 1) * 64 + R * D;
        #pragma unroll
        for (int i = 0; i < S; ++i) xn[i] = xb[i * D];
      }

      float z[8];
      #pragma unroll
      for (int k = 0; k < 8; ++k) {
        float a = w[k * 9] * xv[0];
        #pragma unroll
        for (int j = 1; j < 9; ++j) a = fmaf(w[k * 9 + j], xv[j], a);
        z[k] = a;
      }

      // shaped for v_max3/v_min3 (exact associativity on NaN-free data)
      const float mx = fmaxf(fmaxf(fmaxf(fmaxf(z[0], z[1]), z[2]),
                                   fmaxf(fmaxf(z[3], z[4]), z[5])),
                             fmaxf(z[6], z[7]));
      const float mn = fminf(fminf(fminf(fminf(z[0], z[1]), z[2]),
                                   fminf(fminf(z[3], z[4]), z[5])),
                             fminf(z[6], z[7]));
      #pragma unroll
      for (int k = 0; k < 8; ++k) {
        cmax[k] += (z[k] == mx) ? z[k] : 0.0f;
        cnt_eq(cmin[k], z[k], mn);
      }

      // Rotate window: next taps j<R come from old j+S; rest from xn.
      #pragma unroll
      for (int j = 0; j < R; ++j) xv[j] = xv[j + S];
      #pragma unroll
      for (int i = 0; i < S; ++i) xv[R + i] = xn[i];
    }

    // it = 15 (t = 960+lane): lane 63 invalid when diff=1. Guard BOTH counts
    // via NaN-ed comparand (z==NaN never true).
    {
      float z[8];
      #pragma unroll
      for (int k = 0; k < 8; ++k) {
        float a = w[k * 9] * xv[0];
        #pragma unroll
        for (int j = 1; j < 9; ++j) a = fmaf(w[k * 9 + j], xv[j], a);
        z[k] = a;
      }
      const float mx = fmaxf(fmaxf(fmaxf(fmaxf(z[0], z[1]), z[2]),
                                   fmaxf(fmaxf(z[3], z[4]), z[5])),
                             fmaxf(z[6], z[7]));
      const float mn = fminf(fminf(fminf(fminf(z[0], z[1]), z[2]),
                                   fminf(fminf(z[3], z[4]), z[5])),
                             fminf(z[6], z[7]));
      const bool valid = (960 + lane) < Lz;
      const float mx_eff = valid ? mx : qnan;
      const float mn_eff = valid ? mn : qnan;
      #pragma unroll
      for (int k = 0; k < 8; ++k) {
        cmax[k] += (z[k] == mx_eff) ? z[k] : 0.0f;
        cnt_eq(cmin[k], z[k], mn_eff);
      }
    }

    #pragma unroll
    for (int k = 0; k < 8; ++k) cmax[k] = wredf(cmax[k]);
    int cminr[8];
    #pragma unroll
    for (int k = 0; k < 8; ++k) cminr[k] = wredi(cmin[k]);

    if (lane == 63) {
      float4 a0 = make_float4(cmax[0], cmax[1], cmax[2], cmax[3]);
      float4 a1 = make_float4(cmax[4], cmax[5], cmax[6], cmax[7]);
      float4 b0 = make_float4((float)cminr[0], (float)cminr[1],
                              (float)cminr[2], (float)cminr[3]);
      float4 b1 = make_float4((float)cminr[4], (float)cminr[5],
                              (float)cminr[6], (float)cminr[7]);
      float4* pm = (float4*)(outb + g * 8);
      pm[0] = a0; pm[1] = a1;
      float4* pn = (float4*)(outb + 256 + g * 8);
      pn[0] = b0; pn[1] = b1;
    }
  }
}

// Block = (n, r, gh): 4 waves x 2 groups = 8 of the 32 groups of one row.
__global__ void __launch_bounds__(256, 4) hydra_kernel(
    const float* __restrict__ X, const float* __restrict__ W,
    float* __restrict__ out) {
  __shared__ float xs[LDSX];

  const int b = blockIdx.x;
  const int gh = b & 3;
  const int t1 = b >> 2;
  const int r = t1 % 14;             // di*2 + diff
  const int n = t1 / 14;
  const int diff = r & 1;
  const int di = r >> 1;
  const int Lz = 1024 - diff;
  const float* xrow = X + n * 1024;
  const int tid = threadIdx.x;

  // Stage padded input row (zeros in [0,256) and [256+Lz,1536))
  for (int i = tid; i < LDSX; i += 256) {
    int t = i - NPAD;
    float v = 0.0f;
    if (t >= 0 && t < Lz) v = diff ? (xrow[t + 1] - xrow[t]) : xrow[t];
    xs[i] = v;
  }
  __syncthreads();

  const int lane = tid & 63;
  const int wv = tid >> 6;
  const float* wb = W + r * 2304;                    // (di,diff) bank: 256*9
  float* outb = out + (size_t)n * 7168 + r * 512;    // [cmax(256) | cmin(256)]

  switch (di) {
    case 0: conv_body<1 >(xs, diff, lane, wv, gh, wb, outb); break;
    case 1: conv_body<2 >(xs, diff, lane, wv, gh, wb, outb); break;
    case 2: conv_body<4 >(xs, diff, lane, wv, gh, wb, outb); break;
    case 3: conv_body<8 >(xs, diff, lane, wv, gh, wb, outb); break;
    case 4: conv_body<16>(xs, diff, lane, wv, gh, wb, outb); break;
    case 5: conv_body<32>(xs, diff, lane, wv, gh, wb, outb); break;
    default: conv_body<64>(xs, diff, lane, wv, gh, wb, outb); break;
  }
}

extern "C" void kernel_launch(void* const* d_in, const int* in_sizes, int n_in,
                              void* d_out, int out_size, void* d_ws, size_t ws_size,
                              hipStream_t stream) {
  const float* X = (const float*)d_in[0];   // (256,1,1024) f32
  const float* W = (const float*)d_in[1];   // (7,2,256,1,9) f32, normalized
  float* out = (float*)d_out;               // (256,7168) f32
  hydra_kernel<<<dim3(256 * 14 * 4), dim3(256), 0, stream>>>(X, W, out);
}

// Round 11
// 292.243 us; speedup vs baseline: 1.2615x; 1.0025x over previous
//
#include <hip/hip_runtime.h>

#define NPAD 256
#define LDSX 1536

// Pin a wave-uniform value into scalar registers (folds away if already uniform).
__device__ __forceinline__ float to_sgpr(float v) {
  return __int_as_float(__builtin_amdgcn_readfirstlane(__float_as_int(v)));
}

// c += (z == m) ? 1 : 0 in 2 VALU ops (cmp + carry-add). Clobbers vcc.
// m = NaN guards (z==NaN never true).
__device__ __forceinline__ void cnt_eq(int& c, float z, float m) {
  asm("v_cmp_eq_f32 vcc, %1, %2\n\t"
      "v_addc_co_u32 %0, vcc, 0, %0, vcc"
      : "+v"(c) : "v"(z), "v"(m) : "vcc");
}

// Sum across 64 lanes via DPP; valid result lands in lane 63. Pure VALU.
__device__ __forceinline__ float wredf(float x) {
  x += __int_as_float(__builtin_amdgcn_update_dpp(0, __float_as_int(x), 0x111, 0xf, 0xf, true)); // row_shr:1
  x += __int_as_float(__builtin_amdgcn_update_dpp(0, __float_as_int(x), 0x112, 0xf, 0xf, true)); // row_shr:2
  x += __int_as_float(__builtin_amdgcn_update_dpp(0, __float_as_int(x), 0x114, 0xf, 0xf, true)); // row_shr:4
  x += __int_as_float(__builtin_amdgcn_update_dpp(0, __float_as_int(x), 0x118, 0xf, 0xf, true)); // row_shr:8
  x += __int_as_float(__builtin_amdgcn_update_dpp(0, __float_as_int(x), 0x142, 0xa, 0xf, true)); // bcast15 rows 1,3
  x += __int_as_float(__builtin_amdgcn_update_dpp(0, __float_as_int(x), 0x143, 0xc, 0xf, true)); // bcast31 rows 2,3
  return x;
}
__device__ __forceinline__ int wredi(int x) {
  x += __builtin_amdgcn_update_dpp(0, x, 0x111, 0xf, 0xf, true);
  x += __builtin_amdgcn_update_dpp(0, x, 0x112, 0xf, 0xf, true);
  x += __builtin_amdgcn_update_dpp(0, x, 0x114, 0xf, 0xf, true);
  x += __builtin_amdgcn_update_dpp(0, x, 0x118, 0xf, 0xf, true);
  x += __builtin_amdgcn_update_dpp(0, x, 0x142, 0xa, 0xf, true);
  x += __builtin_amdgcn_update_dpp(0, x, 0x143, 0xc, 0xf, true);
  return x;
}

// 8-value max/min trees shaped for v_max3/v_min3 fusion. Exact associativity
// on NaN-free data -> order-invariant bitwise result.
__device__ __forceinline__ float tree_max(const float z[8]) {
  return fmaxf(fmaxf(fmaxf(fmaxf(z[0], z[1]), z[2]),
                     fmaxf(fmaxf(z[3], z[4]), z[5])),
               fmaxf(z[6], z[7]));
}
__device__ __forceinline__ float tree_min(const float z[8]) {
  return fminf(fminf(fminf(fminf(z[0], z[1]), z[2]),
                     fminf(fminf(z[3], z[4]), z[5])),
               fminf(z[6], z[7]));
}

// One wave: 2 groups over all 1024 positions of one (n, di, diff) row.
// ILP x2: each iteration processes positions t=it*128+lane and t+64 together
// (144 independent FMAs, two independent trees, shared accumulators). The two
// positions' taps sit 64 dwords apart from one rebased pointer -> ds_read2_b32.
template <int D>
__device__ __forceinline__ void conv_body(
    const float* __restrict__ xs, int diff, int lane, int wv, int gh,
    const float* __restrict__ wb, float* __restrict__ outb) {
  const int Lz = 1024 - diff;
  const float qnan = __int_as_float(0x7fc00000);

  for (int gp = 0; gp < 2; ++gp) {
    const int g = gh * 8 + wv * 2 + gp;

    // 72 wave-uniform weights in SGPRs (uniform offset -> s_load; rfl folds).
    const float* wg = wb + __builtin_amdgcn_readfirstlane(g * 72);
    float w[72];
    #pragma unroll
    for (int i = 0; i < 72; ++i) w[i] = to_sgpr(wg[i]);

    float cmax[8];
    int cmin[8];
    #pragma unroll
    for (int k = 0; k < 8; ++k) { cmax[k] = 0.0f; cmin[k] = 0; }

    const float* xq = xs + (NPAD - 4 * D) + lane;   // tap-0 address at t=lane

    // it = 0..6: positions it*128+lane (<=895) and +64 (<=959), both < 1023.
    #pragma unroll 2
    for (int it = 0; it < 7; ++it) {
      const float* xb = xq + it * 128;
      float a0[9], a1[9];
      #pragma unroll
      for (int j = 0; j < 9; ++j) { a0[j] = xb[j * D]; a1[j] = xb[64 + j * D]; }

      float z0[8], z1[8];
      #pragma unroll
      for (int k = 0; k < 8; ++k) {
        float s0 = w[k * 9] * a0[0];
        float s1 = w[k * 9] * a1[0];
        #pragma unroll
        for (int j = 1; j < 9; ++j) {
          s0 = fmaf(w[k * 9 + j], a0[j], s0);
          s1 = fmaf(w[k * 9 + j], a1[j], s1);
        }
        z0[k] = s0; z1[k] = s1;
      }

      const float mx0 = tree_max(z0), mn0 = tree_min(z0);
      const float mx1 = tree_max(z1), mn1 = tree_min(z1);
      #pragma unroll
      for (int k = 0; k < 8; ++k) {
        cmax[k] += (z0[k] == mx0) ? z0[k] : 0.0f;
        cmax[k] += (z1[k] == mx1) ? z1[k] : 0.0f;
        cnt_eq(cmin[k], z0[k], mn0);
        cnt_eq(cmin[k], z1[k], mn1);
      }
    }

    // it = 7 peeled: p0 = 896+lane (always valid), p1 = 960+lane (lane 63
    // invalid when diff=1). Guard BOTH counts via NaN-ed comparand.
    {
      const float* xb = xq + 7 * 128;
      float a0[9], a1[9];
      #pragma unroll
      for (int j = 0; j < 9; ++j) { a0[j] = xb[j * D]; a1[j] = xb[64 + j * D]; }

      float z0[8], z1[8];
      #pragma unroll
      for (int k = 0; k < 8; ++k) {
        float s0 = w[k * 9] * a0[0];
        float s1 = w[k * 9] * a1[0];
        #pragma unroll
        for (int j = 1; j < 9; ++j) {
          s0 = fmaf(w[k * 9 + j], a0[j], s0);
          s1 = fmaf(w[k * 9 + j], a1[j], s1);
        }
        z0[k] = s0; z1[k] = s1;
      }

      const float mx0 = tree_max(z0), mn0 = tree_min(z0);
      const float mx1 = tree_max(z1), mn1 = tree_min(z1);
      const bool valid = (960 + lane) < Lz;
      const float mx1e = valid ? mx1 : qnan;
      const float mn1e = valid ? mn1 : qnan;
      #pragma unroll
      for (int k = 0; k < 8; ++k) {
        cmax[k] += (z0[k] == mx0) ? z0[k] : 0.0f;
        cmax[k] += (z1[k] == mx1e) ? z1[k] : 0.0f;
        cnt_eq(cmin[k], z0[k], mn0);
        cnt_eq(cmin[k], z1[k], mn1e);
      }
    }

    #pragma unroll
    for (int k = 0; k < 8; ++k) cmax[k] = wredf(cmax[k]);
    int cminr[8];
    #pragma unroll
    for (int k = 0; k < 8; ++k) cminr[k] = wredi(cmin[k]);

    if (lane == 63) {
      float4 c0 = make_float4(cmax[0], cmax[1], cmax[2], cmax[3]);
      float4 c1 = make_float4(cmax[4], cmax[5], cmax[6], cmax[7]);
      float4 b0 = make_float4((float)cminr[0], (float)cminr[1],
                              (float)cminr[2], (float)cminr[3]);
      float4 b1 = make_float4((float)cminr[4], (float)cminr[5],
                              (float)cminr[6], (float)cminr[7]);
      float4* pm = (float4*)(outb + g * 8);
      pm[0] = c0; pm[1] = c1;
      float4* pn = (float4*)(outb + 256 + g * 8);
      pn[0] = b0; pn[1] = b1;
    }
  }
}

// Block = (n, r, gh): 4 waves x 2 groups = 8 of the 32 groups of one row.
__global__ void __launch_bounds__(256, 5) hydra_kernel(
    const float* __restrict__ X, const float* __restrict__ W,
    float* __restrict__ out) {
  __shared__ float xs[LDSX];

  const int b = blockIdx.x;
  const int gh = b & 3;
  const int t1 = b >> 2;
  const int r = t1 % 14;             // di*2 + diff
  const int n = t1 / 14;
  const int diff = r & 1;
  const int di = r >> 1;
  const int Lz = 1024 - diff;
  const float* xrow = X + n * 1024;
  const int tid = threadIdx.x;

  // Stage padded input row (zeros in [0,256) and [256+Lz,1536))
  for (int i = tid; i < LDSX; i += 256) {
    int t = i - NPAD;
    float v = 0.0f;
    if (t >= 0 && t < Lz) v = diff ? (xrow[t + 1] - xrow[t]) : xrow[t];
    xs[i] = v;
  }
  __syncthreads();

  const int lane = tid & 63;
  const int wv = tid >> 6;
  const float* wb = W + r * 2304;                    // (di,diff) bank: 256*9
  float* outb = out + (size_t)n * 7168 + r * 512;    // [cmax(256) | cmin(256)]

  switch (di) {
    case 0: conv_body<1 >(xs, diff, lane, wv, gh, wb, outb); break;
    case 1: conv_body<2 >(xs, diff, lane, wv, gh, wb, outb); break;
    case 2: conv_body<4 >(xs, diff, lane, wv, gh, wb, outb); break;
    case 3: conv_body<8 >(xs, diff, lane, wv, gh, wb, outb); break;
    case 4: conv_body<16>(xs, diff, lane, wv, gh, wb, outb); break;
    case 5: conv_body<32>(xs, diff, lane, wv, gh, wb, outb); break;
    default: conv_body<64>(xs, diff, lane, wv, gh, wb, outb); break;
  }
}

extern "C" void kernel_launch(void* const* d_in, const int* in_sizes, int n_in,
                              void* d_out, int out_size, void* d_ws, size_t ws_size,
                              hipStream_t stream) {
  const float* X = (const float*)d_in[0];   // (256,1,1024) f32
  const float* W = (const float*)d_in[1];   // (7,2,256,1,9) f32, normalized
  float* out = (float*)d_out;               // (256,7168) f32
  hydra_kernel<<<dim3(256 * 14 * 4), dim3(256), 0, stream>>>(X, W, out);
}